// Round 2
// baseline (202818.652 us; speedup 1.0000x reference)
//
#include <hip/hip_runtime.h>

#define T_STEPS 32768
#define HDIM    1024
#define LDIM    512
#define ADIM    32
#define NWG     128   // workgroups in recurrence kernel
#define NOUT    8     // belief outputs per WG (NWG*NOUT == HDIM)

// ---------------------------------------------------------------------------
// Encoder: z[t,m] = tanh( sum_k obs[t,k]*enc_w[m,k] + enc_b[m] )
// T=32768, M=512, K=128.  Tiled 64x64, two K=64 steps. 256 threads, 4x4/thread.
// LDS: 2 * 64*65*4 = 33 KiB (under the 64 KiB static limit; +1 pad -> no
// bank conflicts on the column reads).
// ---------------------------------------------------------------------------
__global__ __launch_bounds__(256) void encoder_kernel(
    const float* __restrict__ obs,    // (T,128)
    const float* __restrict__ w,      // (512,128)
    const float* __restrict__ b,      // (512)
    float* __restrict__ z)            // (T,512)
{
    __shared__ float As[64][65];
    __shared__ float Bs[64][65];

    const int tile_n = blockIdx.x;  // 0..7   (m tiles)
    const int tile_t = blockIdx.y;  // 0..511 (t tiles)
    const int tid = threadIdx.x;
    const int ty = tid >> 4;   // 0..15 (t rows)
    const int tx = tid & 15;   // 0..15 (m cols)

    float acc[4][4] = {};

    for (int kt = 0; kt < 2; ++kt) {
        // Stage 64x64 obs tile and 64x64 w tile. 4096 floats each / 256 thr.
        #pragma unroll
        for (int it = 0; it < 4; ++it) {
            int lin = it * 1024 + tid * 4;       // multiple of 4
            int r = lin >> 6, c = lin & 63;
            float4 va = *(const float4*)&obs[(size_t)(tile_t * 64 + r) * 128 + kt * 64 + c];
            As[r][c] = va.x; As[r][c+1] = va.y; As[r][c+2] = va.z; As[r][c+3] = va.w;
            float4 vb = *(const float4*)&w[(size_t)(tile_n * 64 + r) * 128 + kt * 64 + c];
            Bs[r][c] = vb.x; Bs[r][c+1] = vb.y; Bs[r][c+2] = vb.z; Bs[r][c+3] = vb.w;
        }
        __syncthreads();

        for (int k = 0; k < 64; ++k) {
            float av[4], bv[4];
            #pragma unroll
            for (int a = 0; a < 4; ++a) av[a] = As[ty * 4 + a][k];
            #pragma unroll
            for (int c = 0; c < 4; ++c) bv[c] = Bs[tx * 4 + c][k];
            #pragma unroll
            for (int a = 0; a < 4; ++a)
                #pragma unroll
                for (int c = 0; c < 4; ++c)
                    acc[a][c] = fmaf(av[a], bv[c], acc[a][c]);
        }
        __syncthreads();
    }

    #pragma unroll
    for (int a = 0; a < 4; ++a) {
        int row = tile_t * 64 + ty * 4 + a;
        #pragma unroll
        for (int c = 0; c < 4; ++c) {
            int col = tile_n * 64 + tx * 4 + c;
            z[(size_t)row * LDIM + col] = tanhf(acc[a][c] + b[col]);
        }
    }
}

// ---------------------------------------------------------------------------
// GRU recurrence. NWG workgroups x 256 threads, cooperative launch.
// WG wg owns outputs i = wg*NOUT .. wg*NOUT+NOUT-1.
// Per output: 3 gate rows (r,z,n) of w_hh (len 1024) and w_ih (len 544),
// sliced across 32 lanes -> 32x3 + 17x3 = 147 weight registers per lane.
// Per-step sync: h(t) written to d_out (agent scope), arrival counter per step.
// ---------------------------------------------------------------------------
__global__ __launch_bounds__(256, 1) void gru_kernel(
    float* __restrict__ out,          // (T, 1024) == beliefs == h sequence
    const float* __restrict__ z_seq,  // (T, 512)
    const float* __restrict__ act,    // (T, 32)
    const float* __restrict__ w_ih,   // (3072, 544)
    const float* __restrict__ w_hh,   // (3072, 1024)
    const float* __restrict__ b_ih,   // (3072)
    const float* __restrict__ b_hh,   // (3072)
    int* __restrict__ counter)        // (T) zeroed before launch
{
    __shared__ float h_lds[HDIM];
    __shared__ float z_lds[LDIM];
    __shared__ float a_lds[ADIM];

    const int tid  = threadIdx.x;
    const int wg   = blockIdx.x;
    const int grp  = tid >> 5;        // 0..7
    const int lane = tid & 31;
    const int i    = wg * NOUT + grp; // global output index 0..1023

    // ---- load weight slices into registers (once) ----
    float whr[32], whz[32], whn[32];
    {
        const float* pr = &w_hh[(size_t)i * HDIM + lane];
        const float* pz = &w_hh[(size_t)(HDIM + i) * HDIM + lane];
        const float* pn = &w_hh[(size_t)(2 * HDIM + i) * HDIM + lane];
        #pragma unroll
        for (int j = 0; j < 32; ++j) {
            whr[j] = pr[32 * j]; whz[j] = pz[32 * j]; whn[j] = pn[32 * j];
        }
    }
    float wir[17], wiz[17], win[17];
    {
        const float* pr = &w_ih[(size_t)i * 544 + lane];
        const float* pz = &w_ih[(size_t)(HDIM + i) * 544 + lane];
        const float* pn = &w_ih[(size_t)(2 * HDIM + i) * 544 + lane];
        #pragma unroll
        for (int j = 0; j < 17; ++j) {   // j=16 -> k = 512+lane (the act part)
            wir[j] = pr[32 * j]; wiz[j] = pz[32 * j]; win[j] = pn[32 * j];
        }
    }
    const float bir  = b_ih[i], biz = b_ih[HDIM + i], bin_ = b_ih[2 * HDIM + i];
    const float bhr  = b_hh[i], bhz = b_hh[HDIM + i], bhn  = b_hh[2 * HDIM + i];

    for (int q = tid; q < HDIM; q += 256) h_lds[q] = 0.0f;
    __syncthreads();

    for (int t = 0; t < T_STEPS; ++t) {
        // ---- stage input-side data (independent of h -> overlaps the wait) ----
        if (tid < 128) {
            float4 v = *(const float4*)&z_seq[(size_t)t * LDIM + tid * 4];
            z_lds[tid * 4 + 0] = v.x; z_lds[tid * 4 + 1] = v.y;
            z_lds[tid * 4 + 2] = v.z; z_lds[tid * 4 + 3] = v.w;
        } else if (tid < 160) {
            int q = tid - 128;
            a_lds[q] = (t == 0) ? 0.0f : act[(size_t)(t - 1) * ADIM + q];
        }

        if (t > 0) {
            if (tid == 0) {
                while (__hip_atomic_load(&counter[t - 1], __ATOMIC_ACQUIRE,
                                         __HIP_MEMORY_SCOPE_AGENT) < NWG) {
                    __builtin_amdgcn_s_sleep(1);
                }
            }
            __syncthreads();
            const float* hsrc = &out[(size_t)(t - 1) * HDIM];
            #pragma unroll
            for (int q = 0; q < 4; ++q) {
                h_lds[tid * 4 + q] = __hip_atomic_load(
                    &hsrc[tid * 4 + q], __ATOMIC_RELAXED, __HIP_MEMORY_SCOPE_AGENT);
            }
        }
        __syncthreads();

        // ---- matvec partials: hh-side (1024) and ih-side (544) ----
        float sr = 0.f, sz = 0.f, sn = 0.f;
        #pragma unroll
        for (int j = 0; j < 32; ++j) {
            float hv = h_lds[lane + 32 * j];
            sr = fmaf(whr[j], hv, sr);
            sz = fmaf(whz[j], hv, sz);
            sn = fmaf(whn[j], hv, sn);
        }
        float gr = 0.f, gz = 0.f, gn = 0.f;
        #pragma unroll
        for (int j = 0; j < 16; ++j) {
            float xv = z_lds[lane + 32 * j];
            gr = fmaf(wir[j], xv, gr);
            gz = fmaf(wiz[j], xv, gz);
            gn = fmaf(win[j], xv, gn);
        }
        {
            float xa = a_lds[lane];
            gr = fmaf(wir[16], xa, gr);
            gz = fmaf(wiz[16], xa, gz);
            gn = fmaf(win[16], xa, gn);
        }

        // r/z gate pre-activations can be combined before reduction; n cannot.
        float vr = sr + gr, vz = sz + gz;
        #pragma unroll
        for (int m = 16; m >= 1; m >>= 1) {
            vr += __shfl_xor(vr, m);
            vz += __shfl_xor(vz, m);
            sn += __shfl_xor(sn, m);
            gn += __shfl_xor(gn, m);
        }

        if (lane == 0) {
            float r  = 1.0f / (1.0f + expf(-(vr + bir + bhr)));
            float zg = 1.0f / (1.0f + expf(-(vz + biz + bhz)));
            float n  = tanhf(gn + bin_ + r * (sn + bhn));
            float hold = h_lds[i];
            float hnew = (1.0f - zg) * n + zg * hold;
            __hip_atomic_store(&out[(size_t)t * HDIM + i], hnew,
                               __ATOMIC_RELAXED, __HIP_MEMORY_SCOPE_AGENT);
        }
        __syncthreads();   // all WG stores drained (vmcnt) before the release
        if (tid == 0) {
            __hip_atomic_fetch_add(&counter[t], 1, __ATOMIC_RELEASE,
                                   __HIP_MEMORY_SCOPE_AGENT);
        }
    }
}

// ---------------------------------------------------------------------------
extern "C" void kernel_launch(void* const* d_in, const int* in_sizes, int n_in,
                              void* d_out, int out_size, void* d_ws, size_t ws_size,
                              hipStream_t stream) {
    const float* obs   = (const float*)d_in[0];
    const float* act   = (const float*)d_in[1];
    const float* enc_w = (const float*)d_in[2];
    const float* enc_b = (const float*)d_in[3];
    const float* w_ih  = (const float*)d_in[4];
    const float* w_hh  = (const float*)d_in[5];
    const float* b_ih  = (const float*)d_in[6];
    const float* b_hh  = (const float*)d_in[7];
    float* out = (float*)d_out;

    // ws layout: [0, T*4) step counters ; then z_seq (T*512 floats)
    int*   counters = (int*)d_ws;
    float* z_seq    = (float*)((char*)d_ws + (size_t)T_STEPS * sizeof(int));

    hipMemsetAsync(counters, 0, (size_t)T_STEPS * sizeof(int), stream);

    encoder_kernel<<<dim3(8, 512), 256, 0, stream>>>(obs, enc_w, enc_b, z_seq);

    void* args[] = {(void*)&out, (void*)&z_seq, (void*)&act, (void*)&w_ih,
                    (void*)&w_hh, (void*)&b_ih, (void*)&b_hh, (void*)&counters};
    hipLaunchCooperativeKernel((void*)gru_kernel, dim3(NWG), dim3(256),
                               args, 0, stream);
}

// Round 3
// 100322.974 us; speedup vs baseline: 2.0217x; 2.0217x over previous
//
#include <hip/hip_runtime.h>
#include <stdint.h>

#define T_STEPS 32768
#define HDIM    1024
#define LDIM    512
#define ADIM    32
#define NWG     128   // workgroups in recurrence kernel
#define NOUT    8     // belief outputs per WG (NWG*NOUT == HDIM)

// ---------------------------------------------------------------------------
// Encoder: z[t,m] = tanh( sum_k obs[t,k]*enc_w[m,k] + enc_b[m] )
// T=32768, M=512, K=128.  Tiled 64x64, two K=64 steps. 256 threads, 4x4/thread.
// ---------------------------------------------------------------------------
__global__ __launch_bounds__(256) void encoder_kernel(
    const float* __restrict__ obs,    // (T,128)
    const float* __restrict__ w,      // (512,128)
    const float* __restrict__ b,      // (512)
    float* __restrict__ z)            // (T,512)
{
    __shared__ float As[64][65];
    __shared__ float Bs[64][65];

    const int tile_n = blockIdx.x;  // 0..7   (m tiles)
    const int tile_t = blockIdx.y;  // 0..511 (t tiles)
    const int tid = threadIdx.x;
    const int ty = tid >> 4;   // 0..15 (t rows)
    const int tx = tid & 15;   // 0..15 (m cols)

    float acc[4][4] = {};

    for (int kt = 0; kt < 2; ++kt) {
        #pragma unroll
        for (int it = 0; it < 4; ++it) {
            int lin = it * 1024 + tid * 4;
            int r = lin >> 6, c = lin & 63;
            float4 va = *(const float4*)&obs[(size_t)(tile_t * 64 + r) * 128 + kt * 64 + c];
            As[r][c] = va.x; As[r][c+1] = va.y; As[r][c+2] = va.z; As[r][c+3] = va.w;
            float4 vb = *(const float4*)&w[(size_t)(tile_n * 64 + r) * 128 + kt * 64 + c];
            Bs[r][c] = vb.x; Bs[r][c+1] = vb.y; Bs[r][c+2] = vb.z; Bs[r][c+3] = vb.w;
        }
        __syncthreads();

        for (int k = 0; k < 64; ++k) {
            float av[4], bv[4];
            #pragma unroll
            for (int a = 0; a < 4; ++a) av[a] = As[ty * 4 + a][k];
            #pragma unroll
            for (int c = 0; c < 4; ++c) bv[c] = Bs[tx * 4 + c][k];
            #pragma unroll
            for (int a = 0; a < 4; ++a)
                #pragma unroll
                for (int c = 0; c < 4; ++c)
                    acc[a][c] = fmaf(av[a], bv[c], acc[a][c]);
        }
        __syncthreads();
    }

    #pragma unroll
    for (int a = 0; a < 4; ++a) {
        int row = tile_t * 64 + ty * 4 + a;
        #pragma unroll
        for (int c = 0; c < 4; ++c) {
            int col = tile_n * 64 + tx * 4 + c;
            z[(size_t)row * LDIM + col] = tanhf(acc[a][c] + b[col]);
        }
    }
}

// ---------------------------------------------------------------------------
// GRU recurrence. NWG x 256 threads, cooperative launch.
// Sync: tag-in-data. h element i of step t is stored as a packed 8-byte word
//   { tag = t+1 (hi32) | float bits (lo32) }  in hbuf[(t&1)*HDIM + i]
// (agent scope). Readers at step t poll hbuf[((t-1)&1)*HDIM + e] until
// tag == t. No contended counter, no separate release/acquire hop.
// Parity reuse is safe: a WG stores h[t] only after its post-load
// __syncthreads, which orders it after all its loads of h[t-2].
// ---------------------------------------------------------------------------
__global__ __launch_bounds__(256, 1) void gru_kernel(
    float* __restrict__ out,          // (T, 1024) == beliefs
    const float* __restrict__ z_seq,  // (T, 512)
    const float* __restrict__ act,    // (T, 32)
    const float* __restrict__ w_ih,   // (3072, 544)
    const float* __restrict__ w_hh,   // (3072, 1024)
    const float* __restrict__ b_ih,   // (3072)
    const float* __restrict__ b_hh,   // (3072)
    uint64_t* __restrict__ hbuf)      // (2, 1024) packed, zeroed before launch
{
    __shared__ float h_lds[HDIM];
    __shared__ float z_lds[LDIM];
    __shared__ float a_lds[ADIM];

    const int tid  = threadIdx.x;
    const int wg   = blockIdx.x;
    const int grp  = tid >> 5;        // 0..7
    const int lane = tid & 31;
    const int i    = wg * NOUT + grp; // global output index 0..1023

    // ---- load weight slices into registers (once) and PIN them ----
    float whr[32], whz[32], whn[32];
    {
        const float* pr = &w_hh[(size_t)i * HDIM + lane];
        const float* pz = &w_hh[(size_t)(HDIM + i) * HDIM + lane];
        const float* pn = &w_hh[(size_t)(2 * HDIM + i) * HDIM + lane];
        #pragma unroll
        for (int j = 0; j < 32; ++j) {
            whr[j] = pr[32 * j]; whz[j] = pz[32 * j]; whn[j] = pn[32 * j];
        }
    }
    float wir[17], wiz[17], win[17];
    {
        const float* pr = &w_ih[(size_t)i * 544 + lane];
        const float* pz = &w_ih[(size_t)(HDIM + i) * 544 + lane];
        const float* pn = &w_ih[(size_t)(2 * HDIM + i) * 544 + lane];
        #pragma unroll
        for (int j = 0; j < 17; ++j) {
            wir[j] = pr[32 * j]; wiz[j] = pz[32 * j]; win[j] = pn[32 * j];
        }
    }
    // Opaque-pin every weight value so the compiler cannot sink the loads
    // into the t-loop (round-2 profile showed VGPR_Count=116 < 147 weights:
    // they were being re-fetched from L2 every step).
    #pragma unroll
    for (int j = 0; j < 32; ++j) {
        asm volatile("" : "+v"(whr[j]), "+v"(whz[j]), "+v"(whn[j]));
    }
    #pragma unroll
    for (int j = 0; j < 17; ++j) {
        asm volatile("" : "+v"(wir[j]), "+v"(wiz[j]), "+v"(win[j]));
    }

    const float bir  = b_ih[i], biz = b_ih[HDIM + i], bin_ = b_ih[2 * HDIM + i];
    const float bhr  = b_hh[i], bhz = b_hh[HDIM + i], bhn  = b_hh[2 * HDIM + i];

    for (int q = tid; q < HDIM; q += 256) h_lds[q] = 0.0f;
    __syncthreads();

    for (int t = 0; t < T_STEPS; ++t) {
        // ---- stage input-side data (independent of h -> overlaps the wait) ----
        if (tid < 128) {
            float4 v = *(const float4*)&z_seq[(size_t)t * LDIM + tid * 4];
            *(float4*)&z_lds[tid * 4] = v;
        } else if (tid < 160) {
            int q = tid - 128;
            a_lds[q] = (t == 0) ? 0.0f : act[(size_t)(t - 1) * ADIM + q];
        }

        if (t > 0) {
            const uint64_t* bp = hbuf + ((size_t)((t - 1) & 1)) * HDIM + tid * 4;
            const uint32_t want = (uint32_t)t;
            uint64_t v[4];
            int done = 0;
            while (done != 0xF) {
                #pragma unroll
                for (int q = 0; q < 4; ++q) {
                    if (!(done & (1 << q))) {
                        v[q] = __hip_atomic_load(bp + q, __ATOMIC_RELAXED,
                                                 __HIP_MEMORY_SCOPE_AGENT);
                    }
                }
                #pragma unroll
                for (int q = 0; q < 4; ++q) {
                    if (!(done & (1 << q)) && (uint32_t)(v[q] >> 32) == want)
                        done |= (1 << q);
                }
            }
            float4 hv;
            hv.x = __uint_as_float((uint32_t)v[0]);
            hv.y = __uint_as_float((uint32_t)v[1]);
            hv.z = __uint_as_float((uint32_t)v[2]);
            hv.w = __uint_as_float((uint32_t)v[3]);
            *(float4*)&h_lds[tid * 4] = hv;
        }
        __syncthreads();

        // ---- matvec partials: hh-side (1024) and ih-side (544) ----
        float sr = 0.f, sz = 0.f, sn = 0.f;
        #pragma unroll
        for (int j = 0; j < 32; ++j) {
            float hv = h_lds[lane + 32 * j];
            sr = fmaf(whr[j], hv, sr);
            sz = fmaf(whz[j], hv, sz);
            sn = fmaf(whn[j], hv, sn);
        }
        float gr = 0.f, gz = 0.f, gn = 0.f;
        #pragma unroll
        for (int j = 0; j < 16; ++j) {
            float xv = z_lds[lane + 32 * j];
            gr = fmaf(wir[j], xv, gr);
            gz = fmaf(wiz[j], xv, gz);
            gn = fmaf(win[j], xv, gn);
        }
        {
            float xa = a_lds[lane];
            gr = fmaf(wir[16], xa, gr);
            gz = fmaf(wiz[16], xa, gz);
            gn = fmaf(win[16], xa, gn);
        }

        float vr = sr + gr, vz = sz + gz;
        #pragma unroll
        for (int m = 16; m >= 1; m >>= 1) {
            vr += __shfl_xor(vr, m);
            vz += __shfl_xor(vz, m);
            sn += __shfl_xor(sn, m);
            gn += __shfl_xor(gn, m);
        }

        if (lane == 0) {
            float r  = 1.0f / (1.0f + expf(-(vr + bir + bhr)));
            float zg = 1.0f / (1.0f + expf(-(vz + biz + bhz)));
            float n  = tanhf(gn + bin_ + r * (sn + bhn));
            float hold = h_lds[i];
            float hnew = (1.0f - zg) * n + zg * hold;
            // critical-path store first: packed tagged h
            uint64_t pk = ((uint64_t)(uint32_t)(t + 1) << 32) |
                          (uint64_t)__float_as_uint(hnew);
            __hip_atomic_store(&hbuf[((size_t)(t & 1)) * HDIM + i], pk,
                               __ATOMIC_RELAXED, __HIP_MEMORY_SCOPE_AGENT);
            out[(size_t)t * HDIM + i] = hnew;   // plain store, off critical path
        }
        __syncthreads();   // protects z_lds/h_lds restage of next iteration
    }
}

// ---------------------------------------------------------------------------
extern "C" void kernel_launch(void* const* d_in, const int* in_sizes, int n_in,
                              void* d_out, int out_size, void* d_ws, size_t ws_size,
                              hipStream_t stream) {
    const float* obs   = (const float*)d_in[0];
    const float* act   = (const float*)d_in[1];
    const float* enc_w = (const float*)d_in[2];
    const float* enc_b = (const float*)d_in[3];
    const float* w_ih  = (const float*)d_in[4];
    const float* w_hh  = (const float*)d_in[5];
    const float* b_ih  = (const float*)d_in[6];
    const float* b_hh  = (const float*)d_in[7];
    float* out = (float*)d_out;

    // ws layout: [0, 16KB) tagged h double-buffer ; [64KB, ...) z_seq
    uint64_t* hbuf  = (uint64_t*)d_ws;
    float*    z_seq = (float*)((char*)d_ws + 65536);

    hipMemsetAsync(hbuf, 0, 2 * HDIM * sizeof(uint64_t), stream);

    encoder_kernel<<<dim3(8, 512), 256, 0, stream>>>(obs, enc_w, enc_b, z_seq);

    void* args[] = {(void*)&out, (void*)&z_seq, (void*)&act, (void*)&w_ih,
                    (void*)&w_hh, (void*)&b_ih, (void*)&b_hh, (void*)&hbuf};
    hipLaunchCooperativeKernel((void*)gru_kernel, dim3(NWG), dim3(256),
                               args, 0, stream);
}

// Round 4
// 94403.162 us; speedup vs baseline: 2.1484x; 1.0627x over previous
//
#include <hip/hip_runtime.h>
#include <stdint.h>

#define T_STEPS 32768
#define HDIM    1024
#define LDIM    512
#define ADIM    32
#define NWG     128   // workgroups in recurrence kernel
#define NOUT    8     // belief outputs per WG (NWG*NOUT == HDIM)

// ---------------------------------------------------------------------------
// Encoder: z[t,m] = tanh( sum_k obs[t,k]*enc_w[m,k] + enc_b[m] )
// T=32768, M=512, K=128.  Tiled 64x64, two K=64 steps. 256 threads, 4x4/thread.
// ---------------------------------------------------------------------------
__global__ __launch_bounds__(256) void encoder_kernel(
    const float* __restrict__ obs,    // (T,128)
    const float* __restrict__ w,      // (512,128)
    const float* __restrict__ b,      // (512)
    float* __restrict__ z)            // (T,512)
{
    __shared__ float As[64][65];
    __shared__ float Bs[64][65];

    const int tile_n = blockIdx.x;  // 0..7   (m tiles)
    const int tile_t = blockIdx.y;  // 0..511 (t tiles)
    const int tid = threadIdx.x;
    const int ty = tid >> 4;   // 0..15 (t rows)
    const int tx = tid & 15;   // 0..15 (m cols)

    float acc[4][4] = {};

    for (int kt = 0; kt < 2; ++kt) {
        #pragma unroll
        for (int it = 0; it < 4; ++it) {
            int lin = it * 1024 + tid * 4;
            int r = lin >> 6, c = lin & 63;
            float4 va = *(const float4*)&obs[(size_t)(tile_t * 64 + r) * 128 + kt * 64 + c];
            As[r][c] = va.x; As[r][c+1] = va.y; As[r][c+2] = va.z; As[r][c+3] = va.w;
            float4 vb = *(const float4*)&w[(size_t)(tile_n * 64 + r) * 128 + kt * 64 + c];
            Bs[r][c] = vb.x; Bs[r][c+1] = vb.y; Bs[r][c+2] = vb.z; Bs[r][c+3] = vb.w;
        }
        __syncthreads();

        for (int k = 0; k < 64; ++k) {
            float av[4], bv[4];
            #pragma unroll
            for (int a = 0; a < 4; ++a) av[a] = As[ty * 4 + a][k];
            #pragma unroll
            for (int c = 0; c < 4; ++c) bv[c] = Bs[tx * 4 + c][k];
            #pragma unroll
            for (int a = 0; a < 4; ++a)
                #pragma unroll
                for (int c = 0; c < 4; ++c)
                    acc[a][c] = fmaf(av[a], bv[c], acc[a][c]);
        }
        __syncthreads();
    }

    #pragma unroll
    for (int a = 0; a < 4; ++a) {
        int row = tile_t * 64 + ty * 4 + a;
        #pragma unroll
        for (int c = 0; c < 4; ++c) {
            int col = tile_n * 64 + tx * 4 + c;
            z[(size_t)row * LDIM + col] = tanhf(acc[a][c] + b[col]);
        }
    }
}

// ---------------------------------------------------------------------------
// GRU recurrence. NWG x 256 threads, cooperative launch.
// Sync: tag-in-data. h element i of step t stored as { tag=t+1 | float bits }
// in hbuf[(t&1)*HDIM + i] (agent scope).
//  - Publication is COALESCED: the WG's 8 h values are staged in LDS, then
//    threads 0..7 (one wave) store 8 contiguous tagged uint64s = one 64B line
//    in a single transaction (round-3 version did 8 stores from 8 different
//    waves to the same line -> serialized line arbitrations).
//  - Polling: tid>=128 only; poller q owns exactly one 64B line (8 words).
//    1 poller/line/WG (was 2), and staging loads (z/act, tid<128) live in
//    different waves so their vmcnt waits never enter the poll loop.
// Parity reuse across t is safe transitively: a WG reaches step t only after
// every WG published step t-1, so no WG still polls parity (t-2).
// ---------------------------------------------------------------------------
__global__ __launch_bounds__(256, 1) void gru_kernel(
    float* __restrict__ out,          // (T, 1024) == beliefs
    const float* __restrict__ z_seq,  // (T, 512)
    const float* __restrict__ act,    // (T, 32)
    const float* __restrict__ w_ih,   // (3072, 544)
    const float* __restrict__ w_hh,   // (3072, 1024)
    const float* __restrict__ b_ih,   // (3072)
    const float* __restrict__ b_hh,   // (3072)
    uint64_t* __restrict__ hbuf)      // (2, 1024) packed, zeroed before launch
{
    __shared__ float h_lds[HDIM];
    __shared__ float z_lds[LDIM];
    __shared__ float a_lds[ADIM];
    __shared__ float h_pub[NOUT];

    const int tid  = threadIdx.x;
    const int wg   = blockIdx.x;
    const int grp  = tid >> 5;        // 0..7
    const int lane = tid & 31;
    const int i    = wg * NOUT + grp; // global output index 0..1023

    // ---- load weight slices into registers (once) and PIN them ----
    float whr[32], whz[32], whn[32];
    {
        const float* pr = &w_hh[(size_t)i * HDIM + lane];
        const float* pz = &w_hh[(size_t)(HDIM + i) * HDIM + lane];
        const float* pn = &w_hh[(size_t)(2 * HDIM + i) * HDIM + lane];
        #pragma unroll
        for (int j = 0; j < 32; ++j) {
            whr[j] = pr[32 * j]; whz[j] = pz[32 * j]; whn[j] = pn[32 * j];
        }
    }
    float wir[17], wiz[17], win[17];
    {
        const float* pr = &w_ih[(size_t)i * 544 + lane];
        const float* pz = &w_ih[(size_t)(HDIM + i) * 544 + lane];
        const float* pn = &w_ih[(size_t)(2 * HDIM + i) * 544 + lane];
        #pragma unroll
        for (int j = 0; j < 17; ++j) {
            wir[j] = pr[32 * j]; wiz[j] = pz[32 * j]; win[j] = pn[32 * j];
        }
    }
    #pragma unroll
    for (int j = 0; j < 32; ++j) {
        asm volatile("" : "+v"(whr[j]), "+v"(whz[j]), "+v"(whn[j]));
    }
    #pragma unroll
    for (int j = 0; j < 17; ++j) {
        asm volatile("" : "+v"(wir[j]), "+v"(wiz[j]), "+v"(win[j]));
    }

    const float bir  = b_ih[i], biz = b_ih[HDIM + i], bin_ = b_ih[2 * HDIM + i];
    const float bhr  = b_hh[i], bhz = b_hh[HDIM + i], bhn  = b_hh[2 * HDIM + i];

    for (int q = tid; q < HDIM; q += 256) h_lds[q] = 0.0f;
    __syncthreads();

    for (int t = 0; t < T_STEPS; ++t) {
        if (tid < 128) {
            // ---- stage input-side data (overlaps other waves' h poll) ----
            float4 v = *(const float4*)&z_seq[(size_t)t * LDIM + tid * 4];
            *(float4*)&z_lds[tid * 4] = v;
            if (tid < ADIM) {
                a_lds[tid] = (t == 0) ? 0.0f : act[(size_t)(t - 1) * ADIM + tid];
            }
        } else if (t > 0) {
            // ---- poll one 64B line (8 tagged words) of h(t-1) ----
            const int q = tid - 128;                 // 0..127 -> line q
            const uint64_t* bp = hbuf + ((size_t)((t - 1) & 1)) * HDIM + q * 8;
            const uint32_t want = (uint32_t)t;
            uint64_t v[8];
            int done = 0;
            while (done != 0xFF) {
                #pragma unroll
                for (int k = 0; k < 8; ++k) {
                    if (!(done & (1 << k))) {
                        v[k] = __hip_atomic_load(bp + k, __ATOMIC_RELAXED,
                                                 __HIP_MEMORY_SCOPE_AGENT);
                    }
                }
                #pragma unroll
                for (int k = 0; k < 8; ++k) {
                    if (!(done & (1 << k)) && (uint32_t)(v[k] >> 32) == want)
                        done |= (1 << k);
                }
            }
            float4 h0, h1;
            h0.x = __uint_as_float((uint32_t)v[0]);
            h0.y = __uint_as_float((uint32_t)v[1]);
            h0.z = __uint_as_float((uint32_t)v[2]);
            h0.w = __uint_as_float((uint32_t)v[3]);
            h1.x = __uint_as_float((uint32_t)v[4]);
            h1.y = __uint_as_float((uint32_t)v[5]);
            h1.z = __uint_as_float((uint32_t)v[6]);
            h1.w = __uint_as_float((uint32_t)v[7]);
            *(float4*)&h_lds[q * 8]     = h0;
            *(float4*)&h_lds[q * 8 + 4] = h1;
        }
        __syncthreads();   // B1: h_lds/z_lds/a_lds ready

        // ---- matvec partials: hh-side (1024) and ih-side (544) ----
        float sr = 0.f, sz = 0.f, sn = 0.f;
        #pragma unroll
        for (int j = 0; j < 32; ++j) {
            float hv = h_lds[lane + 32 * j];
            sr = fmaf(whr[j], hv, sr);
            sz = fmaf(whz[j], hv, sz);
            sn = fmaf(whn[j], hv, sn);
        }
        float gr = 0.f, gz = 0.f, gn = 0.f;
        #pragma unroll
        for (int j = 0; j < 16; ++j) {
            float xv = z_lds[lane + 32 * j];
            gr = fmaf(wir[j], xv, gr);
            gz = fmaf(wiz[j], xv, gz);
            gn = fmaf(win[j], xv, gn);
        }
        {
            float xa = a_lds[lane];
            gr = fmaf(wir[16], xa, gr);
            gz = fmaf(wiz[16], xa, gz);
            gn = fmaf(win[16], xa, gn);
        }

        float vr = sr + gr, vz = sz + gz;
        #pragma unroll
        for (int m = 16; m >= 1; m >>= 1) {
            vr += __shfl_xor(vr, m);
            vz += __shfl_xor(vz, m);
            sn += __shfl_xor(sn, m);
            gn += __shfl_xor(gn, m);
        }

        if (lane == 0) {
            float r  = 1.0f / (1.0f + expf(-(vr + bir + bhr)));
            float zg = 1.0f / (1.0f + expf(-(vz + biz + bhz)));
            float n  = tanhf(gn + bin_ + r * (sn + bhn));
            float hold = h_lds[i];
            h_pub[grp] = (1.0f - zg) * n + zg * hold;
        }
        __syncthreads();   // B2: h_pub complete

        // ---- coalesced publication: one wave writes one 64B tagged line ----
        if (tid < NOUT) {
            uint64_t pk = ((uint64_t)(uint32_t)(t + 1) << 32) |
                          (uint64_t)__float_as_uint(h_pub[tid]);
            __hip_atomic_store(&hbuf[((size_t)(t & 1)) * HDIM + wg * NOUT + tid],
                               pk, __ATOMIC_RELAXED, __HIP_MEMORY_SCOPE_AGENT);
        } else if (tid == NOUT) {
            // out store off the critical path
            float4 o0 = *(const float4*)&h_pub[0];
            float4 o1 = *(const float4*)&h_pub[4];
            *(float4*)&out[(size_t)t * HDIM + wg * NOUT]     = o0;
            *(float4*)&out[(size_t)t * HDIM + wg * NOUT + 4] = o1;
        }
        // next iteration's B1 protects h_pub / h_lds / z_lds reuse
    }
}

// ---------------------------------------------------------------------------
extern "C" void kernel_launch(void* const* d_in, const int* in_sizes, int n_in,
                              void* d_out, int out_size, void* d_ws, size_t ws_size,
                              hipStream_t stream) {
    const float* obs   = (const float*)d_in[0];
    const float* act   = (const float*)d_in[1];
    const float* enc_w = (const float*)d_in[2];
    const float* enc_b = (const float*)d_in[3];
    const float* w_ih  = (const float*)d_in[4];
    const float* w_hh  = (const float*)d_in[5];
    const float* b_ih  = (const float*)d_in[6];
    const float* b_hh  = (const float*)d_in[7];
    float* out = (float*)d_out;

    // ws layout: [0, 16KB) tagged h double-buffer ; [64KB, ...) z_seq
    uint64_t* hbuf  = (uint64_t*)d_ws;
    float*    z_seq = (float*)((char*)d_ws + 65536);

    hipMemsetAsync(hbuf, 0, 2 * HDIM * sizeof(uint64_t), stream);

    encoder_kernel<<<dim3(8, 512), 256, 0, stream>>>(obs, enc_w, enc_b, z_seq);

    void* args[] = {(void*)&out, (void*)&z_seq, (void*)&act, (void*)&w_ih,
                    (void*)&w_hh, (void*)&b_ih, (void*)&b_hh, (void*)&hbuf};
    hipLaunchCooperativeKernel((void*)gru_kernel, dim3(NWG), dim3(256),
                               args, 0, stream);
}